// Round 29
// baseline (60.238 us; speedup 1.0000x reference)
//
#include <hip/hip_runtime.h>

// SSIM loss, 7x7 window, VALID, (64,1,512,512) fp32.
// R29: DUAL-STRIP ILP. Each wave interleaves two independent strips
// (2 dependency chains) -> latency of strip0's tap reads hides under
// strip1's issue+compute and vice versa. Attacks the measured ~60%
// exposed-latency wall (R28: 1071 cy/iter wall, 428 cy VALU, 2 waves/SIMD).
// Body = R20's verified 1-col pk-f32 core (VALU 24us), state duplicated
// with static names (rule #20). VGPR ~130 is free at 2 resident waves/SIMD.
// Grid: gx=2 (256-col blocks) x gy=4 (strip-pairs) x 64 = 512 blocks.

constexpr int B  = 64;
constexpr int H  = 512, W = 512;
constexpr int OH = H - 6, OW = W - 6;     // 506
constexpr int CW = 64;                    // cols per wave
constexpr int BW_ = 4 * CW;               // cols per block (256)
constexpr int SH = 64;                    // rows per strip

typedef float f2 __attribute__((ext_vector_type(2)));

__global__ __launch_bounds__(256)
void ssim_main(const float* __restrict__ X, const float* __restrict__ Y,
               const float* __restrict__ DR, float* __restrict__ partials)
{
    const int tid  = threadIdx.x;
    const int wid  = tid >> 6;
    const int lane = tid & 63;
    const int c0   = blockIdx.x * BW_ + wid * CW;
    const int r0a  = (blockIdx.y * 2 + 0) * SH;     // strip 0 of the pair
    const int r0b  = (blockIdx.y * 2 + 1) * SH;     // strip 1 of the pair
    const int b    = blockIdx.z;

    const int rows_in0 = min(SH, OH - r0a) + 6;     // always 70
    const int rows_in1 = min(SH, OH - r0b) + 6;     // 70, or 64 (last pair)

    const float d  = DR[b];
    const float C1 = (0.01f * d) * (0.01f * d);
    const float C2 = (0.03f * d) * (0.03f * d);
    const float c1s = 2401.0f * C1;
    const float c2s = 2352.0f * C2;

    const float* __restrict__ Xb = X + (size_t)b * H * W;
    const float* __restrict__ Yb = Y + (size_t)b * H * W;

    unsigned off0  = (unsigned)(r0a * W + c0 + lane);
    unsigned hoff0 = (unsigned)(r0a * W + min(c0 + CW + lane, W - 1));
    unsigned off1  = (unsigned)(r0b * W + c0 + lane);
    unsigned hoff1 = (unsigned)(r0b * W + min(c0 + CW + lane, W - 1));

    const bool colvalid = (c0 + lane) < OW;
    const bool is_halo  = lane < 6;

    // [wave][stream][slot][col] {x,y} pairs
    __shared__ f2 rb[4][2][2][CW + 8];

    // ---- stream 0 state ----
    f2 bP0[7], bQ0[7]; float bxy0[7];
    f2 P0 = {0.f,0.f}, Q0 = {0.f,0.f}; float xy0 = 0.f;
    // ---- stream 1 state ----
    f2 bP1[7], bQ1[7]; float bxy1[7];
    f2 P1 = {0.f,0.f}, Q1 = {0.f,0.f}; float xy1 = 0.f;
#pragma unroll
    for (int i = 0; i < 7; ++i) {
        bP0[i]=P0; bQ0[i]=Q0; bxy0[i]=0.f;
        bP1[i]=P1; bQ1[i]=Q1; bxy1[i]=0.f;
    }

    float acc = 0.f;

    // parity prefetch regs per stream
    f2 a_pre0, a_pre1, a_ph0 = {0.f,0.f}, a_ph1 = {0.f,0.f};
    f2 b_pre0, b_pre1, b_ph0 = {0.f,0.f}, b_ph1 = {0.f,0.f};

    // ---- prologue both streams: row0 -> slot0; row1 -> pre1; row2 -> pre0
    {
        f2 p0a; p0a.x = Xb[off0]; p0a.y = Yb[off0];
        f2 h0a = {0.f,0.f};
        if (is_halo) { h0a.x = Xb[hoff0]; h0a.y = Yb[hoff0]; }
        off0 += W; hoff0 += W;
        a_pre1.x = Xb[off0]; a_pre1.y = Yb[off0];
        if (is_halo) { a_ph1.x = Xb[hoff0]; a_ph1.y = Yb[hoff0]; }
        off0 += W; hoff0 += W;
        a_pre0.x = Xb[off0]; a_pre0.y = Yb[off0];
        if (is_halo) { a_ph0.x = Xb[hoff0]; a_ph0.y = Yb[hoff0]; }
        off0 += W; hoff0 += W;

        f2 p0b; p0b.x = Xb[off1]; p0b.y = Yb[off1];
        f2 h0b = {0.f,0.f};
        if (is_halo) { h0b.x = Xb[hoff1]; h0b.y = Yb[hoff1]; }
        off1 += W; hoff1 += W;
        b_pre1.x = Xb[off1]; b_pre1.y = Yb[off1];
        if (is_halo) { b_ph1.x = Xb[hoff1]; b_ph1.y = Yb[hoff1]; }
        off1 += W; hoff1 += W;
        b_pre0.x = Xb[off1]; b_pre0.y = Yb[off1];
        if (is_halo) { b_ph0.x = Xb[hoff1]; b_ph0.y = Yb[hoff1]; }
        off1 += W; hoff1 += W;

        f2* s0 = rb[wid][0][0];
        s0[lane] = p0a;
        if (is_halo) s0[CW + lane] = h0a;
        f2* s1 = rb[wid][1][0];
        s1[lane] = p0b;
        if (is_halo) s1[CW + lane] = h0b;
    }

    for (int rr = 0; rr < 70; rr += 14) {
#pragma unroll
        for (int p = 0; p < 14; ++p) {
            const int r = rr + p;              // r%7 == p%7, r&1 == p&1
            const bool in0 = r < rows_in0;     // block-uniform
            const bool in1 = r < rows_in1;
            constexpr int s7[14] = {0,1,2,3,4,5,6,0,1,2,3,4,5,6};
            const int sp = s7[p];

            // ---- 1) issue BOTH streams' tap reads first ----
            f2 u0,u1,u2,u3,u4,u5,u6;
            if (in0) {
                f2* const rs = rb[wid][0][p & 1];
                u0=rs[lane+0]; u1=rs[lane+1]; u2=rs[lane+2]; u3=rs[lane+3];
                u4=rs[lane+4]; u5=rs[lane+5]; u6=rs[lane+6];
            }
            f2 w0,w1,w2,w3,w4,w5,w6;
            if (in1) {
                f2* const rs = rb[wid][1][p & 1];
                w0=rs[lane+0]; w1=rs[lane+1]; w2=rs[lane+2]; w3=rs[lane+3];
                w4=rs[lane+4]; w5=rs[lane+5]; w6=rs[lane+6];
            }

            // ---- 2) stage next rows, 3) global prefetch, both streams ----
            if (in0 && r + 1 < rows_in0) {
                f2& pr = (p & 1) ? a_pre0 : a_pre1;
                f2& ph = (p & 1) ? a_ph0  : a_ph1;
                f2* const ws = rb[wid][0][(p & 1) ^ 1];
                ws[lane] = pr;
                if (is_halo) ws[CW + lane] = ph;
                if (r + 3 < rows_in0) {
                    pr.x = Xb[off0]; pr.y = Yb[off0];
                    if (is_halo) { ph.x = Xb[hoff0]; ph.y = Yb[hoff0]; }
                    off0 += W; hoff0 += W;
                }
            }
            if (in1 && r + 1 < rows_in1) {
                f2& pr = (p & 1) ? b_pre0 : b_pre1;
                f2& ph = (p & 1) ? b_ph0  : b_ph1;
                f2* const ws = rb[wid][1][(p & 1) ^ 1];
                ws[lane] = pr;
                if (is_halo) ws[CW + lane] = ph;
                if (r + 3 < rows_in1) {
                    pr.x = Xb[off1]; pr.y = Yb[off1];
                    if (is_halo) { ph.x = Xb[hoff1]; ph.y = Yb[hoff1]; }
                    off1 += W; hoff1 += W;
                }
            }

            // ---- 4) compute stream 0 (wait covered by stream1 issue) ----
            if (in0) {
                const f2 s2 = ((u0 + u1) + (u2 + u3)) + ((u4 + u5) + u6);
                f2 q2 = u0 * u0;
                q2 = __builtin_elementwise_fma(u1, u1, q2);
                q2 = __builtin_elementwise_fma(u2, u2, q2);
                q2 = __builtin_elementwise_fma(u3, u3, q2);
                q2 = __builtin_elementwise_fma(u4, u4, q2);
                q2 = __builtin_elementwise_fma(u5, u5, q2);
                q2 = __builtin_elementwise_fma(u6, u6, q2);
                float hxy = u0.x * u0.y;
                hxy = fmaf(u1.x, u1.y, hxy); hxy = fmaf(u2.x, u2.y, hxy);
                hxy = fmaf(u3.x, u3.y, hxy); hxy = fmaf(u4.x, u4.y, hxy);
                hxy = fmaf(u5.x, u5.y, hxy); hxy = fmaf(u6.x, u6.y, hxy);

                P0 += s2 - bP0[sp];  bP0[sp] = s2;
                Q0 += q2 - bQ0[sp];  bQ0[sp] = q2;
                xy0 += hxy - bxy0[sp]; bxy0[sp] = hxy;

                if (r >= 6 && colvalid) {
                    const float p1 = P0.x * P0.y;
                    const float t1 = fmaf(2.f, p1, c1s);
                    const float qv = fmaf(49.f, xy0, -p1);
                    const float t2 = fmaf(2.f, qv, c2s);
                    const float n2 = fmaf(P0.y, P0.y, P0.x * P0.x);
                    const float b1 = n2 + c1s;
                    const float b2 = fmaf(49.f, Q0.x + Q0.y, c2s) - n2;
                    const float den = b1 * b2;
                    float rc = __builtin_amdgcn_rcpf(den);
                    rc = rc * (2.f - den * rc);
                    acc = fmaf(t1 * t2, rc, acc);
                }
            }

            // ---- 5) compute stream 1 (wait covered by compute 0) ----
            if (in1) {
                const f2 s2 = ((w0 + w1) + (w2 + w3)) + ((w4 + w5) + w6);
                f2 q2 = w0 * w0;
                q2 = __builtin_elementwise_fma(w1, w1, q2);
                q2 = __builtin_elementwise_fma(w2, w2, q2);
                q2 = __builtin_elementwise_fma(w3, w3, q2);
                q2 = __builtin_elementwise_fma(w4, w4, q2);
                q2 = __builtin_elementwise_fma(w5, w5, q2);
                q2 = __builtin_elementwise_fma(w6, w6, q2);
                float hxy = w0.x * w0.y;
                hxy = fmaf(w1.x, w1.y, hxy); hxy = fmaf(w2.x, w2.y, hxy);
                hxy = fmaf(w3.x, w3.y, hxy); hxy = fmaf(w4.x, w4.y, hxy);
                hxy = fmaf(w5.x, w5.y, hxy); hxy = fmaf(w6.x, w6.y, hxy);

                P1 += s2 - bP1[sp];  bP1[sp] = s2;
                Q1 += q2 - bQ1[sp];  bQ1[sp] = q2;
                xy1 += hxy - bxy1[sp]; bxy1[sp] = hxy;

                if (r >= 6 && colvalid) {
                    const float p1 = P1.x * P1.y;
                    const float t1 = fmaf(2.f, p1, c1s);
                    const float qv = fmaf(49.f, xy1, -p1);
                    const float t2 = fmaf(2.f, qv, c2s);
                    const float n2 = fmaf(P1.y, P1.y, P1.x * P1.x);
                    const float b1 = n2 + c1s;
                    const float b2 = fmaf(49.f, Q1.x + Q1.y, c2s) - n2;
                    const float den = b1 * b2;
                    float rc = __builtin_amdgcn_rcpf(den);
                    rc = rc * (2.f - den * rc);
                    acc = fmaf(t1 * t2, rc, acc);
                }
            }
        }
    }

    // block reduction: wave shfl, then cross-wave via LDS (single barrier)
    float s = acc;
#pragma unroll
    for (int o = 32; o; o >>= 1) s += __shfl_down(s, o, 64);
    __shared__ float wsum[4];
    if (lane == 0) wsum[wid] = s;
    __syncthreads();
    if (tid == 0) {
        const int bid = (blockIdx.z * gridDim.y + blockIdx.y) * gridDim.x + blockIdx.x;
        partials[bid] = wsum[0] + wsum[1] + wsum[2] + wsum[3];
    }
}

__global__ __launch_bounds__(256)
void ssim_final(const float* __restrict__ partials, int n,
                float* __restrict__ out, float inv_count)
{
    const int tid = threadIdx.x;
    float s = 0.f;
    for (int i = tid; i < n; i += 256) s += partials[i];
#pragma unroll
    for (int o = 32; o; o >>= 1) s += __shfl_down(s, o, 64);
    __shared__ float wsum[4];
    if ((tid & 63) == 0) wsum[tid >> 6] = s;
    __syncthreads();
    if (tid == 0) out[0] = 1.0f - (wsum[0] + wsum[1] + wsum[2] + wsum[3]) * inv_count;
}

extern "C" void kernel_launch(void* const* d_in, const int* in_sizes, int n_in,
                              void* d_out, int out_size, void* d_ws, size_t ws_size,
                              hipStream_t stream)
{
    const float* X  = (const float*)d_in[0];
    const float* Y  = (const float*)d_in[1];
    const float* DR = (const float*)d_in[2];
    float* out      = (float*)d_out;
    float* partials = (float*)d_ws;

    const int gx = (OW + BW_ - 1) / BW_;     // 2
    const int gy = (OH + 2 * SH - 1) / (2 * SH);  // 4 strip-pairs
    dim3 grid(gx, gy, B);                    // 512 blocks, all partials written
    ssim_main<<<grid, 256, 0, stream>>>(X, Y, DR, partials);

    const int n = gx * gy * B;               // 512
    const float inv_count = 1.0f / (float)((long)B * OH * OW);
    ssim_final<<<1, 256, 0, stream>>>(partials, n, out, inv_count);
}

// Round 30
// 57.433 us; speedup vs baseline: 1.0488x; 1.0488x over previous
//
#include <hip/hip_runtime.h>

// SSIM loss, 7x7 window, VALID, (64,1,512,512) fp32.
// R30 = R28 (champion 42.9us: 2 cols/lane, shared-tap b128 reads,
// incremental col B, pk-f32, SH=64) + FUSED final reduction:
// last-block election via device-scope atomics removes the 2nd kernel
// launch (~3-5us of the wall). Counter in d_ws[0] (memset each launch,
// capture-legal); partials published with atomicExch (device-scope,
// cross-XCD visible); elected block reads them back with atomicAdd(p,0)
// (device-coherent loads, immune to stale per-XCD L2). Deterministic:
// sum over all 512 partials after all are published.
// R29 retired: dual-strip-per-wave doubled per-iter DS critical path.

constexpr int B  = 64;
constexpr int H  = 512, W = 512;
constexpr int OH = H - 6, OW = W - 6;     // 506
constexpr int SH = 64;                    // output rows per block
constexpr int NBLOCKS = 8 * 64;           // gy * B = 512

typedef float f2 __attribute__((ext_vector_type(2)));
typedef float f4 __attribute__((ext_vector_type(4)));

__global__ __launch_bounds__(256)
void ssim_main(const float* __restrict__ X, const float* __restrict__ Y,
               const float* __restrict__ DR, float* __restrict__ ws)
{
    int* const counter      = (int*)ws;        // ws[0]
    float* const partials   = ws + 64;         // 256B offset
    float* const out_final  = ws + 32;         // unused slot (kept simple)

    const int tid  = threadIdx.x;
    const int wid  = tid >> 6;
    const int lane = tid & 63;
    const int c0   = wid * 128;             // block spans cols 0..511 (gx=1)
    const int gc   = c0 + 2 * lane;         // col A (even)
    const int r0   = blockIdx.y * SH;
    const int b    = blockIdx.z;

    const int out_rows = min(SH, OH - r0);
    const int rows_in  = out_rows + 6;       // 70, or 64 on last strip (even)

    const float d  = DR[b];
    const float C1 = (0.01f * d) * (0.01f * d);
    const float C2 = (0.03f * d) * (0.03f * d);
    const float c1s = 2401.0f * C1;          // 49^2 * C1
    const float c2s = 2352.0f * C2;          // 48*49 * C2

    const float* __restrict__ Xb = X + (size_t)b * H * W;
    const float* __restrict__ Yb = Y + (size_t)b * H * W;

    unsigned off  = (unsigned)(r0 * W + gc);
    unsigned hoff = (unsigned)(r0 * W + min(c0 + 128 + 2 * lane, W - 2));

    const bool vA = gc < OW;
    const bool vB = gc + 1 < OW;
    const bool is_halo = lane < 3;           // halo cols c0+128 .. c0+133

    // wave-private dual slots: 128 owned + 6 halo f2 entries ({x,y} per col)
    __shared__ __align__(16) f2 rb[4][2][136];

    // per-col state: P=(sx,sy) packed; ss=S(xx+yy); xy=Sxy. 7-row histories.
    f2 bPA[7], bPB[7];
    float bsA[7], bsB[7], bwA[7], bwB[7];
    f2 PA = {0.f,0.f}, PB = {0.f,0.f};
    float ssA = 0.f, ssB = 0.f, xyA = 0.f, xyB = 0.f;
#pragma unroll
    for (int i = 0; i < 7; ++i) {
        bPA[i]=PA; bPB[i]=PB; bsA[i]=0.f; bsB[i]=0.f; bwA[i]=0.f; bwB[i]=0.f;
    }

    float acc = 0.f;

    // parity prefetch (x,y col-pairs); pre1 = odd rows, pre0 = even rows
    f2 px0, py0, px1, py1;
    f2 phx0={0.f,0.f}, phy0={0.f,0.f}, phx1={0.f,0.f}, phy1={0.f,0.f};

    // ---- prologue: row0 -> slot0; row1 -> pre1; row2 -> pre0 ----
    {
        const f2 x0 = *(const f2*)(Xb + off);
        const f2 y0 = *(const f2*)(Yb + off);
        f2 hx0={0.f,0.f}, hy0={0.f,0.f};
        if (is_halo) { hx0 = *(const f2*)(Xb + hoff); hy0 = *(const f2*)(Yb + hoff); }
        off += W; hoff += W;
        px1 = *(const f2*)(Xb + off); py1 = *(const f2*)(Yb + off);
        if (is_halo) { phx1 = *(const f2*)(Xb + hoff); phy1 = *(const f2*)(Yb + hoff); }
        off += W; hoff += W;
        px0 = *(const f2*)(Xb + off); py0 = *(const f2*)(Yb + off);
        if (is_halo) { phx0 = *(const f2*)(Xb + hoff); phy0 = *(const f2*)(Yb + hoff); }
        off += W; hoff += W;

        f2* s0 = rb[wid][0];
        *(f4*)&s0[2*lane] = (f4){x0.x, y0.x, x0.y, y0.y};
        if (is_halo) *(f4*)&s0[128 + 2*lane] = (f4){hx0.x, hy0.x, hx0.y, hy0.y};
    }

    for (int rr = 0; rr < 70; rr += 14) {
#pragma unroll
        for (int p = 0; p < 14; ++p) {
            const int r = rr + p;              // r%7 == p%7, r&1 == p&1
            if (r < rows_in) {                 // block-uniform
                f2* const rslot = rb[wid][p & 1];        // row r (staged)
                f2* const wslot = rb[wid][(p & 1) ^ 1];  // row r+1 dest
                f2& px = (p & 1) ? px0 : px1;            // pair(r+1)
                f2& py = (p & 1) ? py0 : py1;
                f2& phx = (p & 1) ? phx0 : phx1;
                f2& phy = (p & 1) ? phy0 : phy1;

                // 1) tap reads: 4x ds_read_b128 -> cols gc..gc+7
                const f4 q0 = *(const f4*)&rslot[2*lane + 0];
                const f4 q1 = *(const f4*)&rslot[2*lane + 2];
                const f4 q2 = *(const f4*)&rslot[2*lane + 4];
                const f4 q3 = *(const f4*)&rslot[2*lane + 6];

                // 2) stage row r+1 (one b128 + halo); 3) prefetch row r+3
                if (r + 1 < rows_in) {
                    *(f4*)&wslot[2*lane] = (f4){px.x, py.x, px.y, py.y};
                    if (is_halo)
                        *(f4*)&wslot[128 + 2*lane] = (f4){phx.x, phy.x, phx.y, phy.y};
                    if (r + 3 < rows_in) {
                        px = *(const f2*)(Xb + off);
                        py = *(const f2*)(Yb + off);
                        if (is_halo) { phx = *(const f2*)(Xb + hoff);
                                       phy = *(const f2*)(Yb + hoff); }
                        off += W; hoff += W;
                    }
                }

                // 4) compute cols A (taps 0-6) and B (incremental, taps 1-7)
                const f2 t0={q0.x,q0.y}, t1={q0.z,q0.w},
                         t2={q1.x,q1.y}, t3={q1.z,q1.w},
                         t4={q2.x,q2.y}, t5={q2.z,q2.w},
                         t6={q3.x,q3.y}, t7={q3.z,q3.w};

                const f2 s2A = ((t0+t1)+(t2+t3)) + ((t4+t5)+t6);
                const f2 s2B = (s2A - t0) + t7;
                const f2 tsq0 = t0*t0, tsq7 = t7*t7;
                f2 q2A = tsq0;
                q2A = __builtin_elementwise_fma(t1,t1,q2A);
                q2A = __builtin_elementwise_fma(t2,t2,q2A);
                q2A = __builtin_elementwise_fma(t3,t3,q2A);
                q2A = __builtin_elementwise_fma(t4,t4,q2A);
                q2A = __builtin_elementwise_fma(t5,t5,q2A);
                q2A = __builtin_elementwise_fma(t6,t6,q2A);
                const f2 q2B = (q2A - tsq0) + tsq7;
                const float hsA = q2A.x + q2A.y;
                const float hsB = q2B.x + q2B.y;
                const float t0xy = t0.x * t0.y;
                float hxyA = t0xy;
                hxyA = fmaf(t1.x,t1.y,hxyA); hxyA = fmaf(t2.x,t2.y,hxyA);
                hxyA = fmaf(t3.x,t3.y,hxyA); hxyA = fmaf(t4.x,t4.y,hxyA);
                hxyA = fmaf(t5.x,t5.y,hxyA); hxyA = fmaf(t6.x,t6.y,hxyA);
                const float hxyB = fmaf(t7.x, t7.y, hxyA - t0xy);

                // vertical running 7-row window (slot p%7 holds row r-7)
                constexpr int s7[14] = {0,1,2,3,4,5,6,0,1,2,3,4,5,6};
                const int sp = s7[p];
                PA  += s2A  - bPA[sp]; bPA[sp] = s2A;
                ssA += hsA  - bsA[sp]; bsA[sp] = hsA;
                xyA += hxyA - bwA[sp]; bwA[sp] = hxyA;
                PB  += s2B  - bPB[sp]; bPB[sp] = s2B;
                ssB += hsB  - bsB[sp]; bsB[sp] = hsB;
                xyB += hxyB - bwB[sp]; bwB[sp] = hxyB;

                if (r >= 6) {
                    // S = (2 SxSy + c1s)(2(49 Sxy - SxSy) + c2s)
                    //   / (Sx^2+Sy^2+c1s)(49 ss - Sx^2 - Sy^2 + c2s)
                    {   const float p1 = PA.x * PA.y;
                        const float u1 = fmaf(2.f, p1, c1s);
                        const float qv = fmaf(49.f, xyA, -p1);
                        const float u2 = fmaf(2.f, qv, c2s);
                        const float n2 = fmaf(PA.y, PA.y, PA.x * PA.x);
                        const float d1 = n2 + c1s;
                        const float d2 = fmaf(49.f, ssA, c2s) - n2;
                        const float den = d1 * d2;
                        float rc = __builtin_amdgcn_rcpf(den);
                        rc = rc * (2.f - den * rc);
                        acc += vA ? (u1 * u2) * rc : 0.f;
                    }
                    {   const float p1 = PB.x * PB.y;
                        const float u1 = fmaf(2.f, p1, c1s);
                        const float qv = fmaf(49.f, xyB, -p1);
                        const float u2 = fmaf(2.f, qv, c2s);
                        const float n2 = fmaf(PB.y, PB.y, PB.x * PB.x);
                        const float d1 = n2 + c1s;
                        const float d2 = fmaf(49.f, ssB, c2s) - n2;
                        const float den = d1 * d2;
                        float rc = __builtin_amdgcn_rcpf(den);
                        rc = rc * (2.f - den * rc);
                        acc += vB ? (u1 * u2) * rc : 0.f;
                    }
                }
            }
        }
    }

    // block reduction: wave shfl, then cross-wave via LDS
    float s = acc;
#pragma unroll
    for (int o = 32; o; o >>= 1) s += __shfl_down(s, o, 64);
    __shared__ float wsum[4];
    __shared__ int elect;
    if (lane == 0) wsum[wid] = s;
    __syncthreads();
    if (tid == 0) {
        const int bid = blockIdx.z * gridDim.y + blockIdx.y;
        const float part = wsum[0] + wsum[1] + wsum[2] + wsum[3];
        atomicExch(&partials[bid], part);     // device-scope publish
        __threadfence();
        const int prev = atomicAdd(counter, 1);
        elect = (prev == NBLOCKS - 1) ? 1 : 0;
    }
    __syncthreads();
    if (elect) {
        // all 512 partials published; read device-coherently
        float t = 0.f;
        for (int i = tid; i < NBLOCKS; i += 256)
            t += atomicAdd(&partials[i], 0.0f);
#pragma unroll
        for (int o = 32; o; o >>= 1) t += __shfl_down(t, o, 64);
        if (lane == 0) wsum[wid] = t;
        __syncthreads();
        if (tid == 0) {
            const float inv_count = 1.0f / (float)((long)B * OH * OW);
            float* outp = (float*)out_final;  // silence unused warning path
            (void)outp;
            // final result written by launcher-designated pointer below
            ws[1] = 1.0f - (wsum[0] + wsum[1] + wsum[2] + wsum[3]) * inv_count;
        }
    }
}

__global__ __launch_bounds__(64)
void ssim_copyout(const float* __restrict__ ws, float* __restrict__ out)
{
    if (threadIdx.x == 0) out[0] = ws[1];
}

extern "C" void kernel_launch(void* const* d_in, const int* in_sizes, int n_in,
                              void* d_out, int out_size, void* d_ws, size_t ws_size,
                              hipStream_t stream)
{
    const float* X  = (const float*)d_in[0];
    const float* Y  = (const float*)d_in[1];
    const float* DR = (const float*)d_in[2];
    float* ws       = (float*)d_ws;
    float* out      = (float*)d_out;

    // zero the election counter (ws[0]) each launch — capture-legal
    hipMemsetAsync(d_ws, 0, 4, stream);

    dim3 grid(1, 8, B);                  // 512 blocks
    ssim_main<<<grid, 256, 0, stream>>>(X, Y, DR, ws);

    // tiny copy kernel moves the fused result into d_out
    ssim_copyout<<<1, 64, 0, stream>>>(ws, out);
}

// Round 31
// 42.701 us; speedup vs baseline: 1.4107x; 1.3450x over previous
//
#include <hip/hip_runtime.h>

// SSIM loss, 7x7 window, VALID, (64,1,512,512) fp32.
// R31 = R28 verbatim (champion, 42.9us): 2 cols/lane, shared-tap b128
// reads, incremental col B, pk-f32 channel math, SH=64, read-early
// dual-slot LDS, depth-2 parity prefetch, barrier-free wave strips.
// R30's fused reduction retired: atomic tail slowed the main kernel
// (62->72us profiled) and removed no dispatch. R29's dual-strip ILP
// retired: doubled per-iter DS critical path.
// Structural accounting: VALU floor ~25us, memory floor ~21us; the
// remaining gap is dependency-structural LDS/issue latency at 2 waves/SIMD
// (six structural attempts failed to close it).

constexpr int B  = 64;
constexpr int H  = 512, W = 512;
constexpr int OH = H - 6, OW = W - 6;     // 506
constexpr int SH = 64;                    // output rows per block
// wave: 128 cols (2/lane); block: 4 waves = 512 cols; grid (1, 8, 64)

typedef float f2 __attribute__((ext_vector_type(2)));
typedef float f4 __attribute__((ext_vector_type(4)));

__global__ __launch_bounds__(256)
void ssim_main(const float* __restrict__ X, const float* __restrict__ Y,
               const float* __restrict__ DR, float* __restrict__ partials)
{
    const int tid  = threadIdx.x;
    const int wid  = tid >> 6;
    const int lane = tid & 63;
    const int c0   = wid * 128;             // block spans cols 0..511 (gx=1)
    const int gc   = c0 + 2 * lane;         // col A (even)
    const int r0   = blockIdx.y * SH;
    const int b    = blockIdx.z;

    const int out_rows = min(SH, OH - r0);
    const int rows_in  = out_rows + 6;       // 70, or 64 on last strip (even)

    const float d  = DR[b];
    const float C1 = (0.01f * d) * (0.01f * d);
    const float C2 = (0.03f * d) * (0.03f * d);
    const float c1s = 2401.0f * C1;          // 49^2 * C1
    const float c2s = 2352.0f * C2;          // 48*49 * C2

    const float* __restrict__ Xb = X + (size_t)b * H * W;
    const float* __restrict__ Yb = Y + (size_t)b * H * W;

    unsigned off  = (unsigned)(r0 * W + gc);
    unsigned hoff = (unsigned)(r0 * W + min(c0 + 128 + 2 * lane, W - 2));

    const bool vA = gc < OW;
    const bool vB = gc + 1 < OW;
    const bool is_halo = lane < 3;           // halo cols c0+128 .. c0+133

    // wave-private dual slots: 128 owned + 6 halo f2 entries ({x,y} per col)
    __shared__ __align__(16) f2 rb[4][2][136];

    // per-col state: P=(sx,sy) packed; ss=S(xx+yy); xy=Sxy. 7-row histories.
    f2 bPA[7], bPB[7];
    float bsA[7], bsB[7], bwA[7], bwB[7];
    f2 PA = {0.f,0.f}, PB = {0.f,0.f};
    float ssA = 0.f, ssB = 0.f, xyA = 0.f, xyB = 0.f;
#pragma unroll
    for (int i = 0; i < 7; ++i) {
        bPA[i]=PA; bPB[i]=PB; bsA[i]=0.f; bsB[i]=0.f; bwA[i]=0.f; bwB[i]=0.f;
    }

    float acc = 0.f;

    // parity prefetch (x,y col-pairs); pre1 = odd rows, pre0 = even rows
    f2 px0, py0, px1, py1;
    f2 phx0={0.f,0.f}, phy0={0.f,0.f}, phx1={0.f,0.f}, phy1={0.f,0.f};

    // ---- prologue: row0 -> slot0; row1 -> pre1; row2 -> pre0 ----
    {
        const f2 x0 = *(const f2*)(Xb + off);
        const f2 y0 = *(const f2*)(Yb + off);
        f2 hx0={0.f,0.f}, hy0={0.f,0.f};
        if (is_halo) { hx0 = *(const f2*)(Xb + hoff); hy0 = *(const f2*)(Yb + hoff); }
        off += W; hoff += W;
        px1 = *(const f2*)(Xb + off); py1 = *(const f2*)(Yb + off);
        if (is_halo) { phx1 = *(const f2*)(Xb + hoff); phy1 = *(const f2*)(Yb + hoff); }
        off += W; hoff += W;
        px0 = *(const f2*)(Xb + off); py0 = *(const f2*)(Yb + off);
        if (is_halo) { phx0 = *(const f2*)(Xb + hoff); phy0 = *(const f2*)(Yb + hoff); }
        off += W; hoff += W;

        f2* s0 = rb[wid][0];
        *(f4*)&s0[2*lane] = (f4){x0.x, y0.x, x0.y, y0.y};
        if (is_halo) *(f4*)&s0[128 + 2*lane] = (f4){hx0.x, hy0.x, hx0.y, hy0.y};
    }

    for (int rr = 0; rr < 70; rr += 14) {
#pragma unroll
        for (int p = 0; p < 14; ++p) {
            const int r = rr + p;              // r%7 == p%7, r&1 == p&1
            if (r < rows_in) {                 // block-uniform
                f2* const rslot = rb[wid][p & 1];        // row r (staged)
                f2* const wslot = rb[wid][(p & 1) ^ 1];  // row r+1 dest
                f2& px = (p & 1) ? px0 : px1;            // pair(r+1)
                f2& py = (p & 1) ? py0 : py1;
                f2& phx = (p & 1) ? phx0 : phx1;
                f2& phy = (p & 1) ? phy0 : phy1;

                // 1) tap reads: 4x ds_read_b128 -> cols gc..gc+7
                const f4 q0 = *(const f4*)&rslot[2*lane + 0];
                const f4 q1 = *(const f4*)&rslot[2*lane + 2];
                const f4 q2 = *(const f4*)&rslot[2*lane + 4];
                const f4 q3 = *(const f4*)&rslot[2*lane + 6];

                // 2) stage row r+1 (one b128 + halo); 3) prefetch row r+3
                if (r + 1 < rows_in) {
                    *(f4*)&wslot[2*lane] = (f4){px.x, py.x, px.y, py.y};
                    if (is_halo)
                        *(f4*)&wslot[128 + 2*lane] = (f4){phx.x, phy.x, phx.y, phy.y};
                    if (r + 3 < rows_in) {
                        px = *(const f2*)(Xb + off);
                        py = *(const f2*)(Yb + off);
                        if (is_halo) { phx = *(const f2*)(Xb + hoff);
                                       phy = *(const f2*)(Yb + hoff); }
                        off += W; hoff += W;
                    }
                }

                // 4) compute cols A (taps 0-6) and B (incremental, taps 1-7)
                const f2 t0={q0.x,q0.y}, t1={q0.z,q0.w},
                         t2={q1.x,q1.y}, t3={q1.z,q1.w},
                         t4={q2.x,q2.y}, t5={q2.z,q2.w},
                         t6={q3.x,q3.y}, t7={q3.z,q3.w};

                const f2 s2A = ((t0+t1)+(t2+t3)) + ((t4+t5)+t6);
                const f2 s2B = (s2A - t0) + t7;
                const f2 tsq0 = t0*t0, tsq7 = t7*t7;
                f2 q2A = tsq0;
                q2A = __builtin_elementwise_fma(t1,t1,q2A);
                q2A = __builtin_elementwise_fma(t2,t2,q2A);
                q2A = __builtin_elementwise_fma(t3,t3,q2A);
                q2A = __builtin_elementwise_fma(t4,t4,q2A);
                q2A = __builtin_elementwise_fma(t5,t5,q2A);
                q2A = __builtin_elementwise_fma(t6,t6,q2A);
                const f2 q2B = (q2A - tsq0) + tsq7;
                const float hsA = q2A.x + q2A.y;
                const float hsB = q2B.x + q2B.y;
                const float t0xy = t0.x * t0.y;
                float hxyA = t0xy;
                hxyA = fmaf(t1.x,t1.y,hxyA); hxyA = fmaf(t2.x,t2.y,hxyA);
                hxyA = fmaf(t3.x,t3.y,hxyA); hxyA = fmaf(t4.x,t4.y,hxyA);
                hxyA = fmaf(t5.x,t5.y,hxyA); hxyA = fmaf(t6.x,t6.y,hxyA);
                const float hxyB = fmaf(t7.x, t7.y, hxyA - t0xy);

                // vertical running 7-row window (slot p%7 holds row r-7)
                constexpr int s7[14] = {0,1,2,3,4,5,6,0,1,2,3,4,5,6};
                const int sp = s7[p];
                PA  += s2A  - bPA[sp]; bPA[sp] = s2A;
                ssA += hsA  - bsA[sp]; bsA[sp] = hsA;
                xyA += hxyA - bwA[sp]; bwA[sp] = hxyA;
                PB  += s2B  - bPB[sp]; bPB[sp] = s2B;
                ssB += hsB  - bsB[sp]; bsB[sp] = hsB;
                xyB += hxyB - bwB[sp]; bwB[sp] = hxyB;

                if (r >= 6) {
                    // S = (2 SxSy + c1s)(2(49 Sxy - SxSy) + c2s)
                    //   / (Sx^2+Sy^2+c1s)(49 ss - Sx^2 - Sy^2 + c2s)
                    {   const float p1 = PA.x * PA.y;
                        const float u1 = fmaf(2.f, p1, c1s);
                        const float qv = fmaf(49.f, xyA, -p1);
                        const float u2 = fmaf(2.f, qv, c2s);
                        const float n2 = fmaf(PA.y, PA.y, PA.x * PA.x);
                        const float d1 = n2 + c1s;
                        const float d2 = fmaf(49.f, ssA, c2s) - n2;
                        const float den = d1 * d2;
                        float rc = __builtin_amdgcn_rcpf(den);
                        rc = rc * (2.f - den * rc);
                        acc += vA ? (u1 * u2) * rc : 0.f;
                    }
                    {   const float p1 = PB.x * PB.y;
                        const float u1 = fmaf(2.f, p1, c1s);
                        const float qv = fmaf(49.f, xyB, -p1);
                        const float u2 = fmaf(2.f, qv, c2s);
                        const float n2 = fmaf(PB.y, PB.y, PB.x * PB.x);
                        const float d1 = n2 + c1s;
                        const float d2 = fmaf(49.f, ssB, c2s) - n2;
                        const float den = d1 * d2;
                        float rc = __builtin_amdgcn_rcpf(den);
                        rc = rc * (2.f - den * rc);
                        acc += vB ? (u1 * u2) * rc : 0.f;
                    }
                }
            }
        }
    }

    // block reduction: wave shfl, then cross-wave via LDS (single barrier)
    float s = acc;
#pragma unroll
    for (int o = 32; o; o >>= 1) s += __shfl_down(s, o, 64);
    __shared__ float wsum[4];
    if (lane == 0) wsum[wid] = s;
    __syncthreads();
    if (tid == 0) {
        const int bid = blockIdx.z * gridDim.y + blockIdx.y;
        partials[bid] = wsum[0] + wsum[1] + wsum[2] + wsum[3];
    }
}

__global__ __launch_bounds__(256)
void ssim_final(const float* __restrict__ partials, int n,
                float* __restrict__ out, float inv_count)
{
    const int tid = threadIdx.x;
    float s = 0.f;
    for (int i = tid; i < n; i += 256) s += partials[i];
#pragma unroll
    for (int o = 32; o; o >>= 1) s += __shfl_down(s, o, 64);
    __shared__ float wsum[4];
    if ((tid & 63) == 0) wsum[tid >> 6] = s;
    __syncthreads();
    if (tid == 0) out[0] = 1.0f - (wsum[0] + wsum[1] + wsum[2] + wsum[3]) * inv_count;
}

extern "C" void kernel_launch(void* const* d_in, const int* in_sizes, int n_in,
                              void* d_out, int out_size, void* d_ws, size_t ws_size,
                              hipStream_t stream)
{
    const float* X  = (const float*)d_in[0];
    const float* Y  = (const float*)d_in[1];
    const float* DR = (const float*)d_in[2];
    float* out      = (float*)d_out;
    float* partials = (float*)d_ws;

    const int gy = (OH + SH - 1) / SH;   // 8
    dim3 grid(1, gy, B);                 // 512 blocks, every partial slot written
    ssim_main<<<grid, 256, 0, stream>>>(X, Y, DR, partials);

    const int n = gy * B;                // 512
    const float inv_count = 1.0f / (float)((long)B * OH * OW);
    ssim_final<<<1, 256, 0, stream>>>(partials, n, out, inv_count);
}